// Round 1
// baseline (884.010 us; speedup 1.0000x reference)
//
#include <hip/hip_runtime.h>

// Problem constants
#define NEMB 256
#define NOUT 128
#define QSZ  2048
#define NQ   256
#define NS   1024
#define MMT_F 0.999f
#define OMM_F 0.001f
#define INV_TEMP (1.0f/0.07f)
#define NEG_INF_F (-9.0e15f)

// Output offsets (float32 elements, concatenated in return order)
#define OFF_LL   0u            // logits_local  [1024][2049]
#define OFF_LABL 2098176u      // labels_local  [1024]
#define OFF_LG   2099200u      // logits_global [1024][256]
#define OFF_LABG 2361344u      // labels_global [1024]
#define OFF_NQO  2362368u      // new_queue     [256][128][2048]
#define OFF_NI   69471232u     // new_ids       [256][2048]
#define OFF_NP   69995520u     // new_ptr       [256]

// ---------------------------------------------------------------------------
// Kernel 1: projector MLP for the 1024 gathered q-rows and k-rows.
// 8 samples per block, 128 blocks. fp32, momentum weights fused on the fly.
// Also: l_pos -> logits_local[:,0], labels, and zeroing of negT accumulator.
// ---------------------------------------------------------------------------
__global__ __launch_bounds__(256) void k_proj(
    const float* __restrict__ inputs_q, const float* __restrict__ inputs_k,
    const int* __restrict__ idx_q, const int* __restrict__ idx_k,
    const int* __restrict__ q_ids,
    const float* __restrict__ wq1, const float* __restrict__ bq1,
    const float* __restrict__ wq2, const float* __restrict__ bq2,
    const float* __restrict__ wk1, const float* __restrict__ bk1,
    const float* __restrict__ wk2, const float* __restrict__ bk2,
    float* __restrict__ ws_q, float* __restrict__ ws_k,
    float* __restrict__ negT,
    float* __restrict__ out)
{
    __shared__ float in_q[8][256];
    __shared__ float in_k[8][256];
    __shared__ float h_q[8][256];
    __shared__ float h_k[8][256];
    __shared__ float o_q[8][128];
    __shared__ float o_k[8][128];
    __shared__ float inv_n[2][8];

    const int t  = threadIdx.x;
    const int n0 = blockIdx.x * 8;

    // zero the neg-global accumulator: 128 blocks x 256 threads = 32768 slots
    negT[blockIdx.x * 256 + t] = 0.0f;

    // stage 16 input rows (gathered)
    for (int s = 0; s < 8; ++s) {
        int rq = idx_q[n0 + s];
        int rk = idx_k[n0 + s];
        in_q[s][t] = inputs_q[rq * 256 + t];
        in_k[s][t] = inputs_k[rk * 256 + t];
    }
    __syncthreads();

    // GEMM1: hidden[j] for j = t, both paths, 8 samples each
    {
        float accq[8], acck[8];
        const float b1  = bq1[t];
        const float bk1m = bk1[t] * MMT_F + b1 * OMM_F;
#pragma unroll
        for (int s = 0; s < 8; ++s) { accq[s] = b1; acck[s] = bk1m; }
        for (int i = 0; i < 256; ++i) {
            float wq = wq1[i * 256 + t];
            float wk = wk1[i * 256 + t] * MMT_F + wq * OMM_F;
#pragma unroll
            for (int s = 0; s < 8; ++s) {
                accq[s] += in_q[s][i] * wq;
                acck[s] += in_k[s][i] * wk;
            }
        }
#pragma unroll
        for (int s = 0; s < 8; ++s) {
            h_q[s][t] = fmaxf(accq[s], 0.0f);
            h_k[s][t] = fmaxf(acck[s], 0.0f);
        }
    }
    __syncthreads();

    // GEMM2: threads 0..127 -> q path col j; 128..255 -> k path col j
    {
        const int p = t >> 7;
        const int j = t & 127;
        float acc[8];
        const float b2 = p ? (bk2[j] * MMT_F + bq2[j] * OMM_F) : bq2[j];
#pragma unroll
        for (int s = 0; s < 8; ++s) acc[s] = b2;
        const float (*h)[256] = p ? h_k : h_q;
        for (int i = 0; i < 256; ++i) {
            float w;
            if (p) w = wk2[i * 128 + j] * MMT_F + wq2[i * 128 + j] * OMM_F;
            else   w = wq2[i * 128 + j];
#pragma unroll
            for (int s = 0; s < 8; ++s) acc[s] += h[s][i] * w;
        }
        if (p) {
#pragma unroll
            for (int s = 0; s < 8; ++s) o_k[s][j] = acc[s];
        } else {
#pragma unroll
            for (int s = 0; s < 8; ++s) o_q[s][j] = acc[s];
        }
    }
    __syncthreads();

    // L2 norms (16 (path, sample) pairs)
    if (t < 16) {
        const int p = t & 1, s = t >> 1;
        const float* o = p ? o_k[s] : o_q[s];
        float sum = 0.0f;
        for (int j = 0; j < 128; ++j) { float v = o[j]; sum += v * v; }
        inv_n[p][s] = 1.0f / sqrtf(sum);
    }
    __syncthreads();

    // normalize, store to workspace
    if (t < 128) {
        for (int s = 0; s < 8; ++s) {
            float qv = o_q[s][t] * inv_n[0][s];
            float kv = o_k[s][t] * inv_n[1][s];
            o_q[s][t] = qv;
            o_k[s][t] = kv;
            ws_q[(n0 + s) * 128 + t] = qv;
            ws_k[(n0 + s) * 128 + t] = kv;
        }
    }
    __syncthreads();

    // l_pos + labels
    if (t < 8) {
        const int n = n0 + t;
        float lp = 0.0f;
        for (int j = 0; j < 128; ++j) lp += o_q[t][j] * o_k[t][j];
        out[OFF_LL + (size_t)n * 2049] = lp * INV_TEMP;
        out[OFF_LABL + n] = 0.0f;
        out[OFF_LABG + n] = (float)q_ids[n];
    }
}

// ---------------------------------------------------------------------------
// Kernel 2: rank/cols scan + row bucket lists + new_ptr. Single block.
// Thread r owns queue id r and scans the 1024 q_ids in order.
// ---------------------------------------------------------------------------
__global__ __launch_bounds__(256) void k_rank(
    const int* __restrict__ q_ids, const int* __restrict__ queue_ptr,
    int* __restrict__ cols, int* __restrict__ rowlist,
    int* __restrict__ rowstart, int* __restrict__ rowcnt,
    float* __restrict__ out)
{
    __shared__ int qs[NS];
    __shared__ int cnts[NQ];
    __shared__ int starts[NQ];
    const int t = threadIdx.x;
    for (int i = t; i < NS; i += 256) qs[i] = q_ids[i];
    __syncthreads();

    int c = 0;
    for (int n = 0; n < NS; ++n) c += (qs[n] == t) ? 1 : 0;
    cnts[t] = c;
    __syncthreads();

    if (t == 0) {
        int run = 0;
        for (int r = 0; r < NQ; ++r) { starts[r] = run; run += cnts[r]; }
    }
    __syncthreads();

    const int ptr = queue_ptr[t];
    int idx = starts[t];
    int k = 0;
    for (int n = 0; n < NS; ++n) {
        if (qs[n] == t) {
            cols[n] = (ptr + k) & (QSZ - 1);
            rowlist[idx + k] = n;
            ++k;
        }
    }
    rowstart[t] = starts[t];
    rowcnt[t]   = cnts[t];
    out[OFF_NP + t] = (float)((ptr + cnts[t]) & (QSZ - 1));
}

// ---------------------------------------------------------------------------
// Kernel 3: single fused pass over the 256MB queue.
//  grid (4 chunks of 512 cols, 256 rows), block 256, thread owns 2 cols (float2).
//  Per element: l_neg accumulate (<=8 samples staged; group loop for more),
//  column-sum partials (wave shuffle -> atomicAdd into negT[c][r]),
//  new_queue select+write, plus masked logits_local and new_ids.
// ---------------------------------------------------------------------------
#define MAXC 64
#define MAXG 8
__global__ __launch_bounds__(256) void k_queue(
    const float* __restrict__ queue, const int* __restrict__ ids,
    const int* __restrict__ elem_ids,
    const float* __restrict__ ws_q, const float* __restrict__ ws_k,
    const int* __restrict__ cols, const int* __restrict__ rowlist,
    const int* __restrict__ rowstart, const int* __restrict__ rowcnt,
    float* __restrict__ negT,
    float* __restrict__ out)
{
    const int r    = blockIdx.y;
    const int j0   = blockIdx.x * 512;
    const int t    = threadIdx.x;
    const int j    = j0 + t * 2;
    const int lane = t & 63;
    const int wave = t >> 6;

    __shared__ int   lds_n[MAXC];
    __shared__ int   lds_col[MAXC];
    __shared__ int   lds_elem[MAXC];
    __shared__ float q_lds[MAXG][128];
    __shared__ float k_lds[MAXG][128];
    __shared__ float part[4][128];

    int cnt = rowcnt[r];
    if (cnt > MAXC) cnt = MAXC;   // statistically impossible to exceed
    const int start = rowstart[r];

    for (int i = t; i < cnt; i += 256) {
        int n = rowlist[start + i];
        lds_n[i]    = n;
        lds_col[i]  = cols[n];
        lds_elem[i] = elem_ids[n];
    }
    __syncthreads();

    const int2 idv = *(const int2*)&ids[r * QSZ + j];
    int sel0 = -1, sel1 = -1;
    for (int i = 0; i < cnt; ++i) {
        int cc = lds_col[i];
        if (cc == j)     sel0 = i;
        if (cc == j + 1) sel1 = i;
    }

    const float* qrow  = queue + (size_t)r * NOUT * QSZ;
    float*       outq  = out + OFF_NQO + (size_t)r * NOUT * QSZ;
    float*       outll = out + OFF_LL;

    for (int base = 0; base < cnt || base == 0; base += MAXG) {
        int g = cnt - base;
        if (g > MAXG) g = MAXG;
        if (g < 0)    g = 0;

        __syncthreads();
        for (int idx = t; idx < g * 128; idx += 256) {
            int i = idx >> 7, c = idx & 127;
            int n = lds_n[base + i];
            q_lds[i][c] = ws_q[n * 128 + c];
            k_lds[i][c] = ws_k[n * 128 + c];
        }
        __syncthreads();

        float acc0[MAXG], acc1[MAXG];
#pragma unroll
        for (int i = 0; i < MAXG; ++i) { acc0[i] = 0.0f; acc1[i] = 0.0f; }

        for (int c = 0; c < 128; ++c) {
            float2 v = *(const float2*)&qrow[c * QSZ + j];
            if (base == 0) {
                // column-sum partial (old queue) via wave reduce
                float s = v.x + v.y;
#pragma unroll
                for (int off = 32; off >= 1; off >>= 1)
                    s += __shfl_down(s, off, 64);
                if (lane == 0) part[wave][c] = s;
                // new_queue write (old value or enqueued k)
                float o0 = v.x, o1 = v.y;
                if (sel0 >= 0 && sel0 < g) o0 = k_lds[sel0][c];
                if (sel1 >= 0 && sel1 < g) o1 = k_lds[sel1][c];
                *(float2*)&outq[c * QSZ + j] = make_float2(o0, o1);
            } else {
                if (sel0 >= base && sel0 < base + g) outq[c * QSZ + j]     = k_lds[sel0 - base][c];
                if (sel1 >= base && sel1 < base + g) outq[c * QSZ + j + 1] = k_lds[sel1 - base][c];
            }
#pragma unroll
            for (int i = 0; i < MAXG; ++i) {
                if (i < g) {
                    float qv = q_lds[i][c];
                    acc0[i] += qv * v.x;
                    acc1[i] += qv * v.y;
                }
            }
        }

        // masked logits_local for this group's samples
        for (int i = 0; i < g; ++i) {
            int n = lds_n[base + i];
            int e = lds_elem[base + i];
            size_t ro = (size_t)n * 2049 + 1;
            outll[ro + j]     = (idv.x == e) ? NEG_INF_F * INV_TEMP : acc0[i] * INV_TEMP;
            outll[ro + j + 1] = (idv.y == e) ? NEG_INF_F * INV_TEMP : acc1[i] * INV_TEMP;
        }

        if (base == 0) {
            __syncthreads();
            if (t < 128) {
                float tot = part[0][t] + part[1][t] + part[2][t] + part[3][t];
                atomicAdd(&negT[t * 256 + r], tot);
            }
            // new_ids (ints as float)
            int o0 = (sel0 >= 0) ? lds_elem[sel0] : idv.x;
            int o1 = (sel1 >= 0) ? lds_elem[sel1] : idv.y;
            out[OFF_NI + r * QSZ + j]     = (float)o0;
            out[OFF_NI + r * QSZ + j + 1] = (float)o1;
        }
    }
}

// ---------------------------------------------------------------------------
// Kernel 4: logits_global = q @ (negT/2048)^T / TEMP. 4 samples per block.
// ---------------------------------------------------------------------------
__global__ __launch_bounds__(256) void k_global(
    const float* __restrict__ ws_q, const float* __restrict__ negT,
    float* __restrict__ out)
{
    __shared__ float q_lds[4][128];
    const int t  = threadIdx.x;
    const int n0 = blockIdx.x * 4;
    for (int idx = t; idx < 512; idx += 256) {
        int s = idx >> 7, c = idx & 127;
        q_lds[s][c] = ws_q[(n0 + s) * 128 + c];
    }
    __syncthreads();

    float acc[4] = {0.0f, 0.0f, 0.0f, 0.0f};
    for (int c = 0; c < 128; ++c) {
        float w = negT[c * 256 + t];
#pragma unroll
        for (int s = 0; s < 4; ++s) acc[s] += q_lds[s][c] * w;
    }
    const float scale = (1.0f / 2048.0f) * INV_TEMP;
#pragma unroll
    for (int s = 0; s < 4; ++s)
        out[OFF_LG + (size_t)(n0 + s) * 256 + t] = acc[s] * scale;
}

// ---------------------------------------------------------------------------
extern "C" void kernel_launch(void* const* d_in, const int* in_sizes, int n_in,
                              void* d_out, int out_size, void* d_ws, size_t ws_size,
                              hipStream_t stream)
{
    const float* inputs_q  = (const float*)d_in[0];
    const float* inputs_k  = (const float*)d_in[1];
    const int*   idx_q     = (const int*)d_in[2];
    const int*   idx_k     = (const int*)d_in[3];
    const int*   q_ids     = (const int*)d_in[4];
    const int*   elem_ids  = (const int*)d_in[5];
    const float* wq1 = (const float*)d_in[6];
    const float* bq1 = (const float*)d_in[7];
    const float* wq2 = (const float*)d_in[8];
    const float* bq2 = (const float*)d_in[9];
    const float* wk1 = (const float*)d_in[10];
    const float* bk1 = (const float*)d_in[11];
    const float* wk2 = (const float*)d_in[12];
    const float* bk2 = (const float*)d_in[13];
    const float* queue     = (const float*)d_in[14];
    const int*   ids       = (const int*)d_in[15];
    const int*   queue_ptr = (const int*)d_in[16];

    float* out = (float*)d_out;

    // workspace layout
    float* ws_q     = (float*)d_ws;             // 1024*128
    float* ws_k     = ws_q + 1024 * 128;        // 1024*128
    int*   cols     = (int*)(ws_k + 1024 * 128);// 1024
    int*   rowlist  = cols + 1024;              // 1024
    int*   rowstart = rowlist + 1024;           // 256
    int*   rowcnt   = rowstart + 256;           // 256
    float* negT     = (float*)(rowcnt + 256);   // 128*256 (c-major, [c][r])

    k_proj<<<128, 256, 0, stream>>>(inputs_q, inputs_k, idx_q, idx_k, q_ids,
                                    wq1, bq1, wq2, bq2, wk1, bk1, wk2, bk2,
                                    ws_q, ws_k, negT, out);
    k_rank<<<1, 256, 0, stream>>>(q_ids, queue_ptr, cols, rowlist,
                                  rowstart, rowcnt, out);
    k_queue<<<dim3(4, 256), 256, 0, stream>>>(queue, ids, elem_ids, ws_q, ws_k,
                                              cols, rowlist, rowstart, rowcnt,
                                              negT, out);
    k_global<<<256, 256, 0, stream>>>(ws_q, negT, out);
}

// Round 2
// 699.074 us; speedup vs baseline: 1.2645x; 1.2645x over previous
//
#include <hip/hip_runtime.h>

// Problem constants
#define NEMB 256
#define NOUT 128
#define QSZ  2048
#define NQ   256
#define NS   1024
#define MMT_F 0.999f
#define OMM_F 0.001f
#define INV_TEMP (1.0f/0.07f)
#define NEG_INF_F (-9.0e15f)

// Output offsets (float32 elements, concatenated in return order)
#define OFF_LL   0u            // logits_local  [1024][2049]
#define OFF_LABL 2098176u      // labels_local  [1024]
#define OFF_LG   2099200u      // logits_global [1024][256]
#define OFF_LABG 2361344u      // labels_global [1024]
#define OFF_NQO  2362368u      // new_queue     [256][128][2048]
#define OFF_NI   69471232u     // new_ids       [256][2048]
#define OFF_NP   69995520u     // new_ptr       [256]

__device__ __forceinline__ float wave_sum64(float s) {
#pragma unroll
    for (int off = 32; off >= 1; off >>= 1) s += __shfl_down(s, off, 64);
    return s;
}

// ---------------------------------------------------------------------------
// Kernel 1: projector MLP (4 samples/block, 256 blocks) + rank scan (block 256)
// Also zeroes negT and emits l_pos / labels / new_ptr.
// ---------------------------------------------------------------------------
__global__ __launch_bounds__(256) void k_proj(
    const float* __restrict__ inputs_q, const float* __restrict__ inputs_k,
    const int* __restrict__ idx_q, const int* __restrict__ idx_k,
    const int* __restrict__ q_ids, const int* __restrict__ queue_ptr,
    const float* __restrict__ wq1, const float* __restrict__ bq1,
    const float* __restrict__ wq2, const float* __restrict__ bq2,
    const float* __restrict__ wk1, const float* __restrict__ bk1,
    const float* __restrict__ wk2, const float* __restrict__ bk2,
    float* __restrict__ ws_q, float* __restrict__ ws_k,
    int* __restrict__ cols, int* __restrict__ rowlist,
    int* __restrict__ rowstart, int* __restrict__ rowcnt,
    float* __restrict__ negT,
    float* __restrict__ out)
{
    const int t = threadIdx.x;

    if (blockIdx.x == 256) {
        // ---- rank/cols scan, one thread per queue id ----
        __shared__ int qs[NS];
        __shared__ int cnts[NQ];
        __shared__ int starts[NQ];
        for (int i = t; i < NS; i += 256) qs[i] = q_ids[i];
        __syncthreads();
        int c = 0;
        for (int n = 0; n < NS; ++n) c += (qs[n] == t) ? 1 : 0;
        cnts[t] = c;
        __syncthreads();
        if (t == 0) {
            int run = 0;
            for (int r = 0; r < NQ; ++r) { starts[r] = run; run += cnts[r]; }
        }
        __syncthreads();
        const int ptr = queue_ptr[t];
        int idx = starts[t];
        int k = 0;
        for (int n = 0; n < NS; ++n) {
            if (qs[n] == t) {
                cols[n] = (ptr + k) & (QSZ - 1);
                rowlist[idx + k] = n;
                ++k;
            }
        }
        rowstart[t] = starts[t];
        rowcnt[t]   = cnts[t];
        out[OFF_NP + t] = (float)((ptr + cnts[t]) & (QSZ - 1));
        return;
    }

    __shared__ float in_q[4][256];
    __shared__ float in_k[4][256];
    __shared__ float h_q[4][256];
    __shared__ float h_k[4][256];
    __shared__ float o_q[4][128];
    __shared__ float o_k[4][128];
    __shared__ float inv_n[2][4];

    const int n0 = blockIdx.x * 4;

    // zero negT (128x256 floats) using blocks 0..127
    if (blockIdx.x < 128) negT[blockIdx.x * 256 + t] = 0.0f;

    for (int s = 0; s < 4; ++s) {
        in_q[s][t] = inputs_q[idx_q[n0 + s] * 256 + t];
        in_k[s][t] = inputs_k[idx_k[n0 + s] * 256 + t];
    }
    __syncthreads();

    // GEMM1 (hidden unit j = t, both paths)
    {
        float accq[4], acck[4];
        const float b1   = bq1[t];
        const float bk1m = bk1[t] * MMT_F + b1 * OMM_F;
#pragma unroll
        for (int s = 0; s < 4; ++s) { accq[s] = b1; acck[s] = bk1m; }
#pragma unroll 4
        for (int i = 0; i < 256; ++i) {
            float wq = wq1[i * 256 + t];
            float wk = wk1[i * 256 + t] * MMT_F + wq * OMM_F;
#pragma unroll
            for (int s = 0; s < 4; ++s) {
                accq[s] += in_q[s][i] * wq;
                acck[s] += in_k[s][i] * wk;
            }
        }
#pragma unroll
        for (int s = 0; s < 4; ++s) {
            h_q[s][t] = fmaxf(accq[s], 0.0f);
            h_k[s][t] = fmaxf(acck[s], 0.0f);
        }
    }
    __syncthreads();

    // GEMM2: t<128 -> q path, t>=128 -> k path
    {
        const int p = t >> 7;
        const int j = t & 127;
        float acc[4];
        const float b2 = p ? (bk2[j] * MMT_F + bq2[j] * OMM_F) : bq2[j];
#pragma unroll
        for (int s = 0; s < 4; ++s) acc[s] = b2;
        const float (*h)[256] = p ? h_k : h_q;
#pragma unroll 4
        for (int i = 0; i < 256; ++i) {
            float w;
            if (p) w = wk2[i * 128 + j] * MMT_F + wq2[i * 128 + j] * OMM_F;
            else   w = wq2[i * 128 + j];
#pragma unroll
            for (int s = 0; s < 4; ++s) acc[s] += h[s][i] * w;
        }
        if (p) {
#pragma unroll
            for (int s = 0; s < 4; ++s) o_k[s][j] = acc[s];
        } else {
#pragma unroll
            for (int s = 0; s < 4; ++s) o_q[s][j] = acc[s];
        }
    }
    __syncthreads();

    if (t < 8) {
        const int p = t & 1, s = t >> 1;
        const float* o = p ? o_k[s] : o_q[s];
        float sum = 0.0f;
        for (int j = 0; j < 128; ++j) { float v = o[j]; sum += v * v; }
        inv_n[p][s] = 1.0f / sqrtf(sum);
    }
    __syncthreads();

    if (t < 128) {
        for (int s = 0; s < 4; ++s) {
            float qv = o_q[s][t] * inv_n[0][s];
            float kv = o_k[s][t] * inv_n[1][s];
            o_q[s][t] = qv;
            o_k[s][t] = kv;
            ws_q[(n0 + s) * 128 + t] = qv;
            ws_k[(n0 + s) * 128 + t] = kv;
        }
    }
    __syncthreads();

    if (t < 4) {
        const int n = n0 + t;
        float lp = 0.0f;
        for (int j = 0; j < 128; ++j) lp += o_q[t][j] * o_k[t][j];
        out[OFF_LL + (size_t)n * 2049] = lp * INV_TEMP;
        out[OFF_LABL + n] = 0.0f;
        out[OFF_LABG + n] = (float)q_ids[n];
    }
}

// ---------------------------------------------------------------------------
// Kernel 2: single fused pass over the 256MB queue.
// grid (2 chunks x 256 rows), block 256, thread owns 4 slots (float4).
// c-loop manually unrolled x4 for memory-level parallelism.
// ---------------------------------------------------------------------------
#define MAXC 64
#define MAXG 8
__global__ __launch_bounds__(256) void k_queue(
    const float* __restrict__ queue, const int* __restrict__ ids,
    const int* __restrict__ elem_ids,
    const float* __restrict__ ws_q, const float* __restrict__ ws_k,
    const int* __restrict__ cols, const int* __restrict__ rowlist,
    const int* __restrict__ rowstart, const int* __restrict__ rowcnt,
    float* __restrict__ negT,
    float* __restrict__ out)
{
    const int r    = blockIdx.y;
    const int t    = threadIdx.x;
    const int j    = blockIdx.x * 1024 + t * 4;
    const int lane = t & 63;
    const int wave = t >> 6;

    __shared__ int   lds_n[MAXC];
    __shared__ int   lds_col[MAXC];
    __shared__ int   lds_elem[MAXC];
    __shared__ float q_lds[MAXG][128];
    __shared__ float part[4][128];

    int cnt = rowcnt[r];
    if (cnt > MAXC) cnt = MAXC;   // statistically impossible to exceed
    const int start = rowstart[r];

    for (int i = t; i < cnt; i += 256) {
        int n = rowlist[start + i];
        lds_n[i]    = n;
        lds_col[i]  = cols[n];
        lds_elem[i] = elem_ids[n];
    }
    __syncthreads();

    const int4 idv = *(const int4*)&ids[r * QSZ + j];

    // which (if any) enqueued sample lands in each of my 4 slots
    int sel0 = -1, sel1 = -1, sel2 = -1, sel3 = -1;
    for (int i = 0; i < cnt; ++i) {
        int d = lds_col[i] - j;
        if (d == 0) sel0 = i;
        if (d == 1) sel1 = i;
        if (d == 2) sel2 = i;
        if (d == 3) sel3 = i;
    }
    const int kb0 = (sel0 >= 0) ? lds_n[sel0] * 128 : -1;
    const int kb1 = (sel1 >= 0) ? lds_n[sel1] * 128 : -1;
    const int kb2 = (sel2 >= 0) ? lds_n[sel2] * 128 : -1;
    const int kb3 = (sel3 >= 0) ? lds_n[sel3] * 128 : -1;

    // stage q for group 0 (zero-padded to MAXG)
    const int g0 = (cnt < MAXG) ? cnt : MAXG;
    for (int idx = t; idx < MAXG * 128; idx += 256) {
        int i = idx >> 7, c = idx & 127;
        q_lds[i][c] = (i < g0) ? ws_q[lds_n[i] * 128 + c] : 0.0f;
    }
    __syncthreads();

    const float* __restrict__ qrow = queue + (size_t)r * NOUT * QSZ;
    float*       __restrict__ outq = out + OFF_NQO + (size_t)r * NOUT * QSZ;
    float*       __restrict__ outll = out + OFF_LL;

    float4 acc[MAXG];
#pragma unroll
    for (int i = 0; i < MAXG; ++i) acc[i] = make_float4(0.f, 0.f, 0.f, 0.f);

    for (int cb = 0; cb < 128; cb += 4) {
        float4 v[4];
#pragma unroll
        for (int u = 0; u < 4; ++u)
            v[u] = *(const float4*)&qrow[(size_t)(cb + u) * QSZ + j];

        // column-sum partials: 4 independent shuffle chains
#pragma unroll
        for (int u = 0; u < 4; ++u) {
            float s = wave_sum64(v[u].x + v[u].y + v[u].z + v[u].w);
            if (lane == 0) part[wave][cb + u] = s;
        }

        // l_neg FMAs (q_lds rows are zero-padded: no guards)
#pragma unroll
        for (int i = 0; i < MAXG; ++i) {
            float4 qv = *(const float4*)&q_lds[i][cb];
            acc[i].x += qv.x * v[0].x + qv.y * v[1].x + qv.z * v[2].x + qv.w * v[3].x;
            acc[i].y += qv.x * v[0].y + qv.y * v[1].y + qv.z * v[2].y + qv.w * v[3].y;
            acc[i].z += qv.x * v[0].z + qv.y * v[1].z + qv.z * v[2].z + qv.w * v[3].z;
            acc[i].w += qv.x * v[0].w + qv.y * v[1].w + qv.z * v[2].w + qv.w * v[3].w;
        }

        // new_queue write; selected slots pull k from L2-hot ws_k
        float4 kv0, kv1, kv2, kv3;
        if (kb0 >= 0) kv0 = *(const float4*)&ws_k[kb0 + cb];
        if (kb1 >= 0) kv1 = *(const float4*)&ws_k[kb1 + cb];
        if (kb2 >= 0) kv2 = *(const float4*)&ws_k[kb2 + cb];
        if (kb3 >= 0) kv3 = *(const float4*)&ws_k[kb3 + cb];
#pragma unroll
        for (int u = 0; u < 4; ++u) {
            float4 w = v[u];
            if (kb0 >= 0) w.x = ((const float*)&kv0)[u];
            if (kb1 >= 0) w.y = ((const float*)&kv1)[u];
            if (kb2 >= 0) w.z = ((const float*)&kv2)[u];
            if (kb3 >= 0) w.w = ((const float*)&kv3)[u];
            *(float4*)&outq[(size_t)(cb + u) * QSZ + j] = w;
        }
    }

    // reduce column-sum partials across waves, one atomic per (c,r)
    __syncthreads();
    if (t < 128) {
        float tot = part[0][t] + part[1][t] + part[2][t] + part[3][t];
        atomicAdd(&negT[t * 256 + r], tot);
    }

    // masked logits_local for group 0
    for (int i = 0; i < g0; ++i) {
        int n = lds_n[i];
        int e = lds_elem[i];
        size_t ro = (size_t)n * 2049 + 1 + j;
        outll[ro + 0] = (idv.x == e) ? NEG_INF_F * INV_TEMP : acc[i].x * INV_TEMP;
        outll[ro + 1] = (idv.y == e) ? NEG_INF_F * INV_TEMP : acc[i].y * INV_TEMP;
        outll[ro + 2] = (idv.z == e) ? NEG_INF_F * INV_TEMP : acc[i].z * INV_TEMP;
        outll[ro + 3] = (idv.w == e) ? NEG_INF_F * INV_TEMP : acc[i].w * INV_TEMP;
    }

    // new_ids
    {
        float4 nid;
        nid.x = (float)((sel0 >= 0) ? lds_elem[sel0] : idv.x);
        nid.y = (float)((sel1 >= 0) ? lds_elem[sel1] : idv.y);
        nid.z = (float)((sel2 >= 0) ? lds_elem[sel2] : idv.z);
        nid.w = (float)((sel3 >= 0) ? lds_elem[sel3] : idv.w);
        *(float4*)&out[OFF_NI + r * QSZ + j] = nid;
    }

    // rare extra groups (cnt > 8): l_neg only, re-reads the row chunk
    for (int base = MAXG; base < cnt; base += MAXG) {
        int g = cnt - base; if (g > MAXG) g = MAXG;
        __syncthreads();
        for (int idx = t; idx < MAXG * 128; idx += 256) {
            int i = idx >> 7, c = idx & 127;
            q_lds[i][c] = (i < g) ? ws_q[lds_n[base + i] * 128 + c] : 0.0f;
        }
        __syncthreads();
        float4 acc2[MAXG];
#pragma unroll
        for (int i = 0; i < MAXG; ++i) acc2[i] = make_float4(0.f, 0.f, 0.f, 0.f);
        for (int cb = 0; cb < 128; cb += 4) {
            float4 v[4];
#pragma unroll
            for (int u = 0; u < 4; ++u)
                v[u] = *(const float4*)&qrow[(size_t)(cb + u) * QSZ + j];
#pragma unroll
            for (int i = 0; i < MAXG; ++i) {
                float4 qv = *(const float4*)&q_lds[i][cb];
                acc2[i].x += qv.x * v[0].x + qv.y * v[1].x + qv.z * v[2].x + qv.w * v[3].x;
                acc2[i].y += qv.x * v[0].y + qv.y * v[1].y + qv.z * v[2].y + qv.w * v[3].y;
                acc2[i].z += qv.x * v[0].z + qv.y * v[1].z + qv.z * v[2].z + qv.w * v[3].z;
                acc2[i].w += qv.x * v[0].w + qv.y * v[1].w + qv.z * v[2].w + qv.w * v[3].w;
            }
        }
        for (int i = 0; i < g; ++i) {
            int n = lds_n[base + i];
            int e = lds_elem[base + i];
            size_t ro = (size_t)n * 2049 + 1 + j;
            outll[ro + 0] = (idv.x == e) ? NEG_INF_F * INV_TEMP : acc2[i].x * INV_TEMP;
            outll[ro + 1] = (idv.y == e) ? NEG_INF_F * INV_TEMP : acc2[i].y * INV_TEMP;
            outll[ro + 2] = (idv.z == e) ? NEG_INF_F * INV_TEMP : acc2[i].z * INV_TEMP;
            outll[ro + 3] = (idv.w == e) ? NEG_INF_F * INV_TEMP : acc2[i].w * INV_TEMP;
        }
    }
}

// ---------------------------------------------------------------------------
// Kernel 3: logits_global = q @ (negT/2048)^T / TEMP. 4 samples per block.
// ---------------------------------------------------------------------------
__global__ __launch_bounds__(256) void k_global(
    const float* __restrict__ ws_q, const float* __restrict__ negT,
    float* __restrict__ out)
{
    __shared__ float q_lds[4][128];
    const int t  = threadIdx.x;
    const int n0 = blockIdx.x * 4;
    for (int idx = t; idx < 512; idx += 256) {
        int s = idx >> 7, c = idx & 127;
        q_lds[s][c] = ws_q[(n0 + s) * 128 + c];
    }
    __syncthreads();

    float acc[4] = {0.0f, 0.0f, 0.0f, 0.0f};
#pragma unroll 4
    for (int c = 0; c < 128; ++c) {
        float w = negT[c * 256 + t];
#pragma unroll
        for (int s = 0; s < 4; ++s) acc[s] += q_lds[s][c] * w;
    }
    const float scale = (1.0f / 2048.0f) * INV_TEMP;
#pragma unroll
    for (int s = 0; s < 4; ++s)
        out[OFF_LG + (size_t)(n0 + s) * 256 + t] = acc[s] * scale;
}

// ---------------------------------------------------------------------------
extern "C" void kernel_launch(void* const* d_in, const int* in_sizes, int n_in,
                              void* d_out, int out_size, void* d_ws, size_t ws_size,
                              hipStream_t stream)
{
    const float* inputs_q  = (const float*)d_in[0];
    const float* inputs_k  = (const float*)d_in[1];
    const int*   idx_q     = (const int*)d_in[2];
    const int*   idx_k     = (const int*)d_in[3];
    const int*   q_ids     = (const int*)d_in[4];
    const int*   elem_ids  = (const int*)d_in[5];
    const float* wq1 = (const float*)d_in[6];
    const float* bq1 = (const float*)d_in[7];
    const float* wq2 = (const float*)d_in[8];
    const float* bq2 = (const float*)d_in[9];
    const float* wk1 = (const float*)d_in[10];
    const float* bk1 = (const float*)d_in[11];
    const float* wk2 = (const float*)d_in[12];
    const float* bk2 = (const float*)d_in[13];
    const float* queue     = (const float*)d_in[14];
    const int*   ids       = (const int*)d_in[15];
    const int*   queue_ptr = (const int*)d_in[16];

    float* out = (float*)d_out;

    // workspace layout
    float* ws_q     = (float*)d_ws;             // 1024*128
    float* ws_k     = ws_q + 1024 * 128;        // 1024*128
    int*   cols     = (int*)(ws_k + 1024 * 128);// 1024
    int*   rowlist  = cols + 1024;              // 1024
    int*   rowstart = rowlist + 1024;           // 256
    int*   rowcnt   = rowstart + 256;           // 256
    float* negT     = (float*)(rowcnt + 256);   // 128*256 (c-major, [c][r])

    k_proj<<<257, 256, 0, stream>>>(inputs_q, inputs_k, idx_q, idx_k, q_ids,
                                    queue_ptr,
                                    wq1, bq1, wq2, bq2, wk1, bk1, wk2, bk2,
                                    ws_q, ws_k, cols, rowlist, rowstart, rowcnt,
                                    negT, out);
    k_queue<<<dim3(2, 256), 256, 0, stream>>>(queue, ids, elem_ids, ws_q, ws_k,
                                              cols, rowlist, rowstart, rowcnt,
                                              negT, out);
    k_global<<<256, 256, 0, stream>>>(ws_q, negT, out);
}